// Round 1
// baseline (33.623 us; speedup 1.0000x reference)
//
#include <hip/hip_runtime.h>

#define H2C 450
#define WC 1242
#define HC 375
#define NPTS 4000000
#define NPIX (H2C * WC)   // 558900

// d_ws layout: [0..48) floats: P_cam(16) | P_lid(16) | M(16); winner int[NPIX] at byte 256.

__device__ __forceinline__ void mm4(float* o, const float* a, const float* b) {
    // o = a @ b ; k-sequential FMA chain (BLAS sgemm-like rounding)
    for (int i = 0; i < 4; i++)
        for (int j = 0; j < 4; j++) {
            float t = a[i * 4 + 0] * b[0 * 4 + j];
            t = fmaf(a[i * 4 + 1], b[1 * 4 + j], t);
            t = fmaf(a[i * 4 + 2], b[2 * 4 + j], t);
            t = fmaf(a[i * 4 + 3], b[3 * 4 + j], t);
            o[i * 4 + j] = t;
        }
}

__global__ void setup_k(const float* __restrict__ K, const float* __restrict__ C,
                        const float* __restrict__ L, float* __restrict__ mats) {
#pragma clang fp contract(off)
    if (threadIdx.x != 0 || blockIdx.x != 0) return;
    float Pc[16], Pl[16], A[16], X[16], M[16];
    mm4(Pc, K, C);
    mm4(Pl, K, L);
    for (int i = 0; i < 16; i++) A[i] = Pl[i];
    // LAPACK sgetrf (unblocked, partial pivot, reciprocal scaling)
    int piv[4];
    for (int k = 0; k < 4; k++) {
        int p = k; float mx = fabsf(A[k * 4 + k]);
        for (int i = k + 1; i < 4; i++) { float v = fabsf(A[i * 4 + k]); if (v > mx) { mx = v; p = i; } }
        piv[k] = p;
        if (p != k) for (int j = 0; j < 4; j++) { float t = A[k * 4 + j]; A[k * 4 + j] = A[p * 4 + j]; A[p * 4 + j] = t; }
        float akk = A[k * 4 + k];
        if (fabsf(akk) >= 1.17549435e-38f) {
            float r = 1.0f / akk;
            for (int i = k + 1; i < 4; i++) A[i * 4 + k] = A[i * 4 + k] * r;
        } else {
            for (int i = k + 1; i < 4; i++) A[i * 4 + k] = A[i * 4 + k] / akk;
        }
        for (int i = k + 1; i < 4; i++) {
            float lik = A[i * 4 + k];
            for (int j = k + 1; j < 4; j++) A[i * 4 + j] = A[i * 4 + j] - lik * A[k * 4 + j];
        }
    }
    // getrs: solve A X = I (column-wise axpy order, matching reference strsm)
    for (int i = 0; i < 16; i++) X[i] = 0.0f;
    X[0] = X[5] = X[10] = X[15] = 1.0f;
    for (int k = 0; k < 4; k++) if (piv[k] != k)
        for (int j = 0; j < 4; j++) { float t = X[k * 4 + j]; X[k * 4 + j] = X[piv[k] * 4 + j]; X[piv[k] * 4 + j] = t; }
    for (int j = 0; j < 4; j++) {
        // forward: L (unit lower)
        for (int k = 0; k < 4; k++) {
            float xk = X[k * 4 + j];
            for (int i = k + 1; i < 4; i++) X[i * 4 + j] = X[i * 4 + j] - xk * A[i * 4 + k];
        }
        // backward: U (non-unit upper), LAPACK order: divide then axpy upward
        for (int k = 3; k >= 0; k--) {
            float xk = X[k * 4 + j] / A[k * 4 + k];
            X[k * 4 + j] = xk;
            for (int i = 0; i < k; i++) X[i * 4 + j] = X[i * 4 + j] - xk * A[i * 4 + k];
        }
    }
    mm4(M, Pc, X);
    for (int i = 0; i < 16; i++) { mats[i] = Pc[i]; mats[16 + i] = Pl[i]; mats[32 + i] = M[i]; }
}

__global__ void init_k(float4* __restrict__ fi4, int4* __restrict__ winner4) {
    int i = blockIdx.x * blockDim.x + threadIdx.x;
    if (i < NPTS / 4) fi4[i] = make_float4(0.f, 0.f, 0.f, 0.f);
    if (i < NPIX / 4) winner4[i] = make_int4(-1, -1, -1, -1);   // 558900 = 4*139725 exactly
}

__global__ void point_k(const float4* __restrict__ velo, const float* __restrict__ mats,
                        int* __restrict__ winner) {
    int i = blockIdx.x * blockDim.x + threadIdx.x;
    if (i >= NPTS) return;
    float4 v = velo[i];
    const float* Pc = mats;
    const float* Pl = mats + 16;
    float vp0 = fmaf(v.w, Pc[3],  fmaf(v.z, Pc[2],  fmaf(v.y, Pc[1], v.x * Pc[0])));
    float vp1 = fmaf(v.w, Pc[7],  fmaf(v.z, Pc[6],  fmaf(v.y, Pc[5], v.x * Pc[4])));
    float vz  = fmaf(v.w, Pc[11], fmaf(v.z, Pc[10], fmaf(v.y, Pc[9], v.x * Pc[8])));
    float vx = vp0 / vz;
    float vy = vp1 / vz;
    bool onimg = (v.x > 0.f) && (vx > 0.f) && (vx < (float)WC) && (vy > 0.f) && (vy < (float)HC);
    float nv0 = fmaf(v.w, Pl[3],  fmaf(v.z, Pl[2],  fmaf(v.y, Pl[1], v.x * Pl[0])));
    float nv1 = fmaf(v.w, Pl[7],  fmaf(v.z, Pl[6],  fmaf(v.y, Pl[5], v.x * Pl[4])));
    float nz  = fmaf(v.w, Pl[11], fmaf(v.z, Pl[10], fmaf(v.y, Pl[9], v.x * Pl[8])));
    float nx = nv0 / nz;
    float ny = nv1 / nz;
    float rx = rintf(nx);   // round half to even == jnp.round
    float ry = rintf(ny);
    // float-domain bounds checks reproduce numpy int32-cast outcomes (NaN/huge -> invalid)
    if (onimg && (nz > 0.f) && (rx >= 0.f) && (rx < (float)WC) && (ry >= 0.f) && (ry < (float)H2C)) {
        int px = (int)rx, py = (int)ry;
        atomicMax(&winner[py * WC + px], i);   // last-write-wins == max index wins
    }
}

__global__ void resolve_k(const float* __restrict__ depth, const float4* __restrict__ velo,
                          const float* __restrict__ mats, const int* __restrict__ winner,
                          float* __restrict__ img, float* __restrict__ noocc,
                          float* __restrict__ org, float* __restrict__ fi) {
#pragma clang fp contract(off)
    int p = blockIdx.x * blockDim.x + threadIdx.x;
    if (p >= NPIX) return;
    int wi = winner[p];
    float o0, o1, o2, o3, o4, o5, o6;
    if (wi >= 0) {
        float4 v = velo[wi];
        const float* Pc = mats;
        const float* Pl = mats + 16;
        float vp0 = fmaf(v.w, Pc[3],  fmaf(v.z, Pc[2],  fmaf(v.y, Pc[1], v.x * Pc[0])));
        float vp1 = fmaf(v.w, Pc[7],  fmaf(v.z, Pc[6],  fmaf(v.y, Pc[5], v.x * Pc[4])));
        float vz  = fmaf(v.w, Pc[11], fmaf(v.z, Pc[10], fmaf(v.y, Pc[9], v.x * Pc[8])));
        float nv0 = fmaf(v.w, Pl[3],  fmaf(v.z, Pl[2],  fmaf(v.y, Pl[1], v.x * Pl[0])));
        float nv1 = fmaf(v.w, Pl[7],  fmaf(v.z, Pl[6],  fmaf(v.y, Pl[5], v.x * Pl[4])));
        float nz  = fmaf(v.w, Pl[11], fmaf(v.z, Pl[10], fmaf(v.y, Pl[9], v.x * Pl[8])));
        o0 = nv0 / nz; o1 = nv1 / nz; o2 = nz;
        o3 = vp0 / vz; o4 = vp1 / vz; o5 = vz;
        o6 = (float)wi;
        noocc[p] = 1.0f;
        org[p] = 1.0f;
        fi[wi] = 1.0f;   // winners are unique per pixel -> no write conflict
    } else {
        noocc[p] = 0.0f;
        org[p] = 0.0f;
        float d = depth[p];
        if (d > 0.0f) {
            int y = p / WC, x = p - y * WC;
            float fx = (float)x, fy = (float)y;
            const float* M = mats + 32;
            float p0 = fx * d, p1 = fy * d;
            // np.einsum: plain left-to-right mul/add, no FMA (contract off above)
            float pp0 = ((p0 * M[0] + p1 * M[1]) + d * M[2]) + M[3];
            float pp1 = ((p0 * M[4] + p1 * M[5]) + d * M[6]) + M[7];
            float pp2 = ((p0 * M[8] + p1 * M[9]) + d * M[10]) + M[11];
            float zs = (pp2 != 0.0f) ? pp2 : 1.0f;
            o0 = fx; o1 = fy; o2 = d;
            o3 = pp0 / zs; o4 = pp1 / zs; o5 = pp2;
            o6 = 0.0f;
        } else {
            o0 = o1 = o2 = o3 = o4 = o5 = o6 = 0.0f;
        }
    }
    float* ip = img + (size_t)p * 7;
    ip[0] = o0; ip[1] = o1; ip[2] = o2; ip[3] = o3; ip[4] = o4; ip[5] = o5; ip[6] = o6;
}

extern "C" void kernel_launch(void* const* d_in, const int* in_sizes, int n_in,
                              void* d_out, int out_size, void* d_ws, size_t ws_size,
                              hipStream_t stream) {
    const float* velo  = (const float*)d_in[0];
    const float* K     = (const float*)d_in[1];
    const float* C     = (const float*)d_in[2];
    const float* L     = (const float*)d_in[3];
    const float* depth = (const float*)d_in[4];

    float* out   = (float*)d_out;
    float* img   = out;                       // NPIX*7
    float* noocc = out + (size_t)NPIX * 7;    // NPIX
    float* org   = noocc + NPIX;              // NPIX
    float* fi    = org + NPIX;                // NPTS

    float* mats  = (float*)d_ws;
    int* winner  = (int*)((char*)d_ws + 256);

    setup_k<<<1, 64, 0, stream>>>(K, C, L, mats);

    int initN = NPTS / 4;   // covers fi (1M float4) and winner (139725 int4)
    init_k<<<(initN + 255) / 256, 256, 0, stream>>>((float4*)fi, (int4*)winner);

    point_k<<<(NPTS + 255) / 256, 256, 0, stream>>>((const float4*)velo, mats, winner);

    resolve_k<<<(NPIX + 255) / 256, 256, 0, stream>>>(depth, (const float4*)velo, mats, winner,
                                                      img, noocc, org, fi);
}

// Round 2
// 28.797 us; speedup vs baseline: 1.1676x; 1.1676x over previous
//
#include <hip/hip_runtime.h>

#define H2C 450
#define WC 1242
#define HC 375
#define NPTS 4000000
#define NPIX (H2C * WC)   // 558900

// d_ws layout: [0..48) floats: P_cam(16) | P_lid(16) | M(16); winner int[NPIX] at byte 256.

__device__ __forceinline__ void mm4(float* o, const float* a, const float* b) {
    // o = a @ b ; k-sequential FMA chain (BLAS sgemm-like rounding). Bit-identical to round 1.
    for (int i = 0; i < 4; i++)
        for (int j = 0; j < 4; j++) {
            float t = a[i * 4 + 0] * b[0 * 4 + j];
            t = fmaf(a[i * 4 + 1], b[1 * 4 + j], t);
            t = fmaf(a[i * 4 + 2], b[2 * 4 + j], t);
            t = fmaf(a[i * 4 + 3], b[3 * 4 + j], t);
            o[i * 4 + j] = t;
        }
}

// Combined: winner = -1 fill (all threads) + mats computation (global thread 0).
__global__ void init_mats_k(const float* __restrict__ K, const float* __restrict__ C,
                            const float* __restrict__ L, float* __restrict__ mats,
                            int4* __restrict__ winner4) {
#pragma clang fp contract(off)
    int i = blockIdx.x * blockDim.x + threadIdx.x;
    if (i < NPIX / 4) winner4[i] = make_int4(-1, -1, -1, -1);   // 558900 = 4*139725 exactly
    if (i != 0) return;
    float Pc[16], Pl[16], A[16], X[16], M[16];
    mm4(Pc, K, C);
    mm4(Pl, K, L);
    for (int k = 0; k < 16; k++) A[k] = Pl[k];
    // LAPACK sgetrf (unblocked, partial pivot, reciprocal scaling) — bit-identical to round 1
    int piv[4];
    for (int k = 0; k < 4; k++) {
        int p = k; float mx = fabsf(A[k * 4 + k]);
        for (int r = k + 1; r < 4; r++) { float v = fabsf(A[r * 4 + k]); if (v > mx) { mx = v; p = r; } }
        piv[k] = p;
        if (p != k) for (int j = 0; j < 4; j++) { float t = A[k * 4 + j]; A[k * 4 + j] = A[p * 4 + j]; A[p * 4 + j] = t; }
        float akk = A[k * 4 + k];
        if (fabsf(akk) >= 1.17549435e-38f) {
            float r = 1.0f / akk;
            for (int r2 = k + 1; r2 < 4; r2++) A[r2 * 4 + k] = A[r2 * 4 + k] * r;
        } else {
            for (int r2 = k + 1; r2 < 4; r2++) A[r2 * 4 + k] = A[r2 * 4 + k] / akk;
        }
        for (int r = k + 1; r < 4; r++) {
            float lik = A[r * 4 + k];
            for (int j = k + 1; j < 4; j++) A[r * 4 + j] = A[r * 4 + j] - lik * A[k * 4 + j];
        }
    }
    // getrs: solve A X = I (column-wise axpy order)
    for (int k = 0; k < 16; k++) X[k] = 0.0f;
    X[0] = X[5] = X[10] = X[15] = 1.0f;
    for (int k = 0; k < 4; k++) if (piv[k] != k)
        for (int j = 0; j < 4; j++) { float t = X[k * 4 + j]; X[k * 4 + j] = X[piv[k] * 4 + j]; X[piv[k] * 4 + j] = t; }
    for (int j = 0; j < 4; j++) {
        for (int k = 0; k < 4; k++) {
            float xk = X[k * 4 + j];
            for (int r = k + 1; r < 4; r++) X[r * 4 + j] = X[r * 4 + j] - xk * A[r * 4 + k];
        }
        for (int k = 3; k >= 0; k--) {
            float xk = X[k * 4 + j] / A[k * 4 + k];
            X[k * 4 + j] = xk;
            for (int r = 0; r < k; r++) X[r * 4 + j] = X[r * 4 + j] - xk * A[r * 4 + k];
        }
    }
    mm4(M, Pc, X);
    for (int k = 0; k < 16; k++) { mats[k] = Pc[k]; mats[16 + k] = Pl[k]; mats[32 + k] = M[k]; }
}

__global__ void point_k(const float4* __restrict__ velo, const float* __restrict__ mats,
                        int* __restrict__ winner, float* __restrict__ fi) {
    int i = blockIdx.x * blockDim.x + threadIdx.x;
    if (i >= NPTS) return;
    fi[i] = 0.0f;   // fi zero-fill fused here; resolve_k overwrites winners after this kernel completes
    float4 v = velo[i];
    const float* Pc = mats;
    const float* Pl = mats + 16;
    float vp0 = fmaf(v.w, Pc[3],  fmaf(v.z, Pc[2],  fmaf(v.y, Pc[1], v.x * Pc[0])));
    float vp1 = fmaf(v.w, Pc[7],  fmaf(v.z, Pc[6],  fmaf(v.y, Pc[5], v.x * Pc[4])));
    float vz  = fmaf(v.w, Pc[11], fmaf(v.z, Pc[10], fmaf(v.y, Pc[9], v.x * Pc[8])));
    float vx = vp0 / vz;
    float vy = vp1 / vz;
    bool onimg = (v.x > 0.f) && (vx > 0.f) && (vx < (float)WC) && (vy > 0.f) && (vy < (float)HC);
    float nv0 = fmaf(v.w, Pl[3],  fmaf(v.z, Pl[2],  fmaf(v.y, Pl[1], v.x * Pl[0])));
    float nv1 = fmaf(v.w, Pl[7],  fmaf(v.z, Pl[6],  fmaf(v.y, Pl[5], v.x * Pl[4])));
    float nz  = fmaf(v.w, Pl[11], fmaf(v.z, Pl[10], fmaf(v.y, Pl[9], v.x * Pl[8])));
    float nx = nv0 / nz;
    float ny = nv1 / nz;
    float rx = rintf(nx);   // round half to even == jnp.round
    float ry = rintf(ny);
    // float-domain bounds checks reproduce numpy int32-cast outcomes (NaN/huge -> invalid)
    if (onimg && (nz > 0.f) && (rx >= 0.f) && (rx < (float)WC) && (ry >= 0.f) && (ry < (float)H2C)) {
        int px = (int)rx, py = (int)ry;
        atomicMax(&winner[py * WC + px], i);   // last-write-wins == max index wins
    }
}

__global__ void __launch_bounds__(256)
resolve_k(const float* __restrict__ depth, const float4* __restrict__ velo,
          const float* __restrict__ mats, const int* __restrict__ winner,
          float* __restrict__ img, float* __restrict__ noocc,
          float* __restrict__ org, float* __restrict__ fi) {
#pragma clang fp contract(off)
    __shared__ float srec[256 * 7];
    int pb = blockIdx.x * 256;
    int p = pb + threadIdx.x;
    int valid = NPIX - pb; if (valid > 256) valid = 256;
    float o0 = 0.f, o1 = 0.f, o2 = 0.f, o3 = 0.f, o4 = 0.f, o5 = 0.f, o6 = 0.f;
    if (p < NPIX) {
        int wi = winner[p];
        if (wi >= 0) {
            float4 v = velo[wi];
            const float* Pc = mats;
            const float* Pl = mats + 16;
            float vp0 = fmaf(v.w, Pc[3],  fmaf(v.z, Pc[2],  fmaf(v.y, Pc[1], v.x * Pc[0])));
            float vp1 = fmaf(v.w, Pc[7],  fmaf(v.z, Pc[6],  fmaf(v.y, Pc[5], v.x * Pc[4])));
            float vz  = fmaf(v.w, Pc[11], fmaf(v.z, Pc[10], fmaf(v.y, Pc[9], v.x * Pc[8])));
            float nv0 = fmaf(v.w, Pl[3],  fmaf(v.z, Pl[2],  fmaf(v.y, Pl[1], v.x * Pl[0])));
            float nv1 = fmaf(v.w, Pl[7],  fmaf(v.z, Pl[6],  fmaf(v.y, Pl[5], v.x * Pl[4])));
            float nz  = fmaf(v.w, Pl[11], fmaf(v.z, Pl[10], fmaf(v.y, Pl[9], v.x * Pl[8])));
            o0 = nv0 / nz; o1 = nv1 / nz; o2 = nz;
            o3 = vp0 / vz; o4 = vp1 / vz; o5 = vz;
            o6 = (float)wi;
            noocc[p] = 1.0f;
            org[p] = 1.0f;
            fi[wi] = 1.0f;   // winners are unique per pixel -> no write conflict
        } else {
            noocc[p] = 0.0f;
            org[p] = 0.0f;
            float d = depth[p];
            if (d > 0.0f) {
                int y = p / WC, x = p - y * WC;
                float fx = (float)x, fy = (float)y;
                const float* M = mats + 32;
                float p0 = fx * d, p1 = fy * d;
                // np.einsum: plain left-to-right mul/add, no FMA (contract off above)
                float pp0 = ((p0 * M[0] + p1 * M[1]) + d * M[2]) + M[3];
                float pp1 = ((p0 * M[4] + p1 * M[5]) + d * M[6]) + M[7];
                float pp2 = ((p0 * M[8] + p1 * M[9]) + d * M[10]) + M[11];
                float zs = (pp2 != 0.0f) ? pp2 : 1.0f;
                o0 = fx; o1 = fy; o2 = d;
                o3 = pp0 / zs; o4 = pp1 / zs; o5 = pp2;
                o6 = 0.0f;
            }
        }
    }
    // stage the 7-float record in LDS, then write back fully coalesced
    float* r = srec + threadIdx.x * 7;
    r[0] = o0; r[1] = o1; r[2] = o2; r[3] = o3; r[4] = o4; r[5] = o5; r[6] = o6;
    __syncthreads();
    float* obase = img + (size_t)pb * 7;
    int nfl = valid * 7;
    for (int k = threadIdx.x; k < nfl; k += 256) obase[k] = srec[k];
}

extern "C" void kernel_launch(void* const* d_in, const int* in_sizes, int n_in,
                              void* d_out, int out_size, void* d_ws, size_t ws_size,
                              hipStream_t stream) {
    const float* velo  = (const float*)d_in[0];
    const float* K     = (const float*)d_in[1];
    const float* C     = (const float*)d_in[2];
    const float* L     = (const float*)d_in[3];
    const float* depth = (const float*)d_in[4];

    float* out   = (float*)d_out;
    float* img   = out;                       // NPIX*7
    float* noocc = out + (size_t)NPIX * 7;    // NPIX
    float* org   = noocc + NPIX;              // NPIX
    float* fi    = org + NPIX;                // NPTS

    float* mats  = (float*)d_ws;
    int* winner  = (int*)((char*)d_ws + 256);

    // winner-init covers 139725 int4 elements -> 546 blocks; thread 0 computes mats
    init_mats_k<<<(NPIX / 4 + 255) / 256, 256, 0, stream>>>(K, C, L, mats, (int4*)winner);

    point_k<<<(NPTS + 255) / 256, 256, 0, stream>>>((const float4*)velo, mats, winner, fi);

    resolve_k<<<(NPIX + 255) / 256, 256, 0, stream>>>(depth, (const float4*)velo, mats, winner,
                                                      img, noocc, org, fi);
}